// Round 2
// baseline (45.569 us; speedup 1.0000x reference)
//
#include <hip/hip_runtime.h>
#include <math.h>

#define B 1000
#define D 8
#define PRE 98
#define NEXT 512
#define SC 32
#define ANT 5
#define BM 16
#define NT ((B + BM - 1) / BM)  // 63 tiles of 16 rows

// ---------------------------------------------------------------------------
// Kernel 1: per (d, 16-row tile): GEMM1 + bias + relu + LayerNorm + GEMM2
//           + bias + relu, scaled by coef -> part[d][b][c]
// 512 threads (8 waves). coef computed in-block (replaces old k_coef).
// ---------------------------------------------------------------------------
__global__ __launch_bounds__(512) void k_main(const float* __restrict__ x,
                                              const float* __restrict__ sub_w,
                                              const float* __restrict__ sub_b,
                                              const float* __restrict__ gamma,
                                              const float* __restrict__ beta,
                                              const float* __restrict__ cut_w,
                                              const float* __restrict__ cut_b,
                                              const float* __restrict__ b_mat,
                                              const float* __restrict__ h_mat,
                                              const float* __restrict__ a_mat,
                                              const int* __restrict__ k_idx,
                                              float* __restrict__ part) {
    __shared__ float x_lds[BM][PRE];
    __shared__ float h_lds[BM][NEXT];
    __shared__ float mu_s[BM], rs_s[BM];
    __shared__ float coef_s[SC];

    int t = threadIdx.x;
    int d = blockIdx.x / NT;
    int tile = blockIdx.x - d * NT;
    int b0 = tile * BM;

    // ---- coef for this d (32 threads) ----
    if (t < SC) {
        int c = t;
        int kk = k_idx[c];
        float s = 0.f;
#pragma unroll
        for (int a = 0; a < ANT; ++a)
            s += h_mat[(d * SC + kk) * ANT + a] * a_mat[c * ANT + a];
        coef_s[c] = b_mat[d * SC + c] * s;
    }

    // ---- stage x tile into LDS (zero-fill rows past B) ----
    for (int idx = t; idx < BM * PRE; idx += 512) {
        int r = idx / PRE, i = idx - r * PRE;
        int b = b0 + r;
        x_lds[r][i] = (b < B) ? x[b * (D * PRE) + d * PRE + i] : 0.f;
    }
    __syncthreads();

    // ---- GEMM1: h = relu(x_tile @ sub_w[d] + sub_b[d]) ----
    // thread -> 4 rows x 4 consecutive columns, prefetched K loop
    int cl = t & 127;       // column quad: cols cl*4 .. cl*4+3
    int r0 = (t >> 7) * 4;  // rows r0 .. r0+3
    float acc[4][4];
#pragma unroll
    for (int r = 0; r < 4; ++r)
#pragma unroll
        for (int i = 0; i < 4; ++i) acc[r][i] = 0.f;

    const float* swp = sub_w + d * PRE * NEXT + cl * 4;
    float4 w = *reinterpret_cast<const float4*>(swp);
#pragma unroll 2
    for (int k = 0; k < PRE - 1; ++k) {
        float4 wn = *reinterpret_cast<const float4*>(swp + (k + 1) * NEXT);
#pragma unroll
        for (int r = 0; r < 4; ++r) {
            float xv = x_lds[r0 + r][k];
            acc[r][0] = fmaf(xv, w.x, acc[r][0]);
            acc[r][1] = fmaf(xv, w.y, acc[r][1]);
            acc[r][2] = fmaf(xv, w.z, acc[r][2]);
            acc[r][3] = fmaf(xv, w.w, acc[r][3]);
        }
        w = wn;
    }
#pragma unroll
    for (int r = 0; r < 4; ++r) {
        float xv = x_lds[r0 + r][PRE - 1];
        acc[r][0] = fmaf(xv, w.x, acc[r][0]);
        acc[r][1] = fmaf(xv, w.y, acc[r][1]);
        acc[r][2] = fmaf(xv, w.z, acc[r][2]);
        acc[r][3] = fmaf(xv, w.w, acc[r][3]);
    }
    float4 bb = *reinterpret_cast<const float4*>(sub_b + d * NEXT + cl * 4);
#pragma unroll
    for (int r = 0; r < 4; ++r) {
        float4 hv;
        hv.x = fmaxf(acc[r][0] + bb.x, 0.f);
        hv.y = fmaxf(acc[r][1] + bb.y, 0.f);
        hv.z = fmaxf(acc[r][2] + bb.z, 0.f);
        hv.w = fmaxf(acc[r][3] + bb.w, 0.f);
        *reinterpret_cast<float4*>(&h_lds[r0 + r][cl * 4]) = hv;
    }
    __syncthreads();

    // ---- LayerNorm stats: 32 threads per row, shuffle reduce ----
    {
        int row = t >> 5, l = t & 31;
        float s1 = 0.f, s2 = 0.f;
        for (int o = l; o < NEXT; o += 32) {
            float v = h_lds[row][o];
            s1 += v;
            s2 += v * v;
        }
#pragma unroll
        for (int off = 16; off >= 1; off >>= 1) {
            s1 += __shfl_xor(s1, off);
            s2 += __shfl_xor(s2, off);
        }
        if (l == 0) {
            float mu = s1 * (1.f / NEXT);
            float var = s2 * (1.f / NEXT) - mu * mu;
            mu_s[row] = mu;
            rs_s[row] = rsqrtf(var + 1e-5f);
        }
    }
    __syncthreads();

    // ---- normalize in place (+ gamma/beta) ----
    {
        const float* g = gamma + d * NEXT;
        const float* bt = beta + d * NEXT;
        for (int idx = t; idx < BM * NEXT; idx += 512) {
            int r = idx >> 9, o = idx & (NEXT - 1);
            h_lds[r][o] = (h_lds[r][o] - mu_s[r]) * rs_s[r] * g[o] + bt[o];
        }
    }
    __syncthreads();

    // ---- GEMM2: cut = relu(h @ cut_w[d] + cut_b[d]); part = cut * coef ----
    {
        int c = t & 31, row = t >> 5;  // 512 threads = 16 rows x 32 cols
        float s = 0.f;
        const float* cw = cut_w + d * NEXT * SC + c;
#pragma unroll 8
        for (int o = 0; o < NEXT; ++o) s = fmaf(h_lds[row][o], cw[o * SC], s);
        float cb = cut_b[d * SC + c];
        int b = b0 + row;
        if (b < B) part[(d * B + b) * SC + c] = fmaxf(s + cb, 0.f) * coef_s[c];
    }
}

// ---------------------------------------------------------------------------
// Kernel 2: tail MLP. One wave per row b: z(32)->fc3(98)->fc4(49)->out(10)
//           -> log_softmax.  B = 1000 = 250 blocks * 4 waves exactly.
// ---------------------------------------------------------------------------
__global__ __launch_bounds__(256) void k_tail(const float* __restrict__ part,
                                              const float* __restrict__ noise,
                                              const float* __restrict__ a_mat,
                                              const float* __restrict__ clb,
                                              const float* __restrict__ fc3_w,
                                              const float* __restrict__ fc3_b,
                                              const float* __restrict__ fc4_w,
                                              const float* __restrict__ fc4_b,
                                              const float* __restrict__ out_w,
                                              const float* __restrict__ out_b,
                                              float* __restrict__ out) {
    __shared__ float w3[SC * 98];
    __shared__ float w4[98 * 49];
    __shared__ float wo[49 * 10];
    __shared__ float b3[98], b4[49], bo[10];
    __shared__ float z_s[4][SC];
    __shared__ float z3_s[4][98];
    __shared__ float z4_s[4][49];

    int t = threadIdx.x;
    for (int i = t; i < SC * 98; i += 256) w3[i] = fc3_w[i];
    for (int i = t; i < 98 * 49; i += 256) w4[i] = fc4_w[i];
    for (int i = t; i < 49 * 10; i += 256) wo[i] = out_w[i];
    if (t < 98) b3[t] = fc3_b[t];
    if (t < 49) b4[t] = fc4_b[t];
    if (t < 10) bo[t] = out_b[t];
    __syncthreads();

    int w = t >> 6, lane = t & 63;
    int b = blockIdx.x * 4 + w;

    // z = relu(sum_d part + noise . a_mat + cut_layer_bias)
    if (lane < SC) {
        int j = lane;
        float s = clb[j];
#pragma unroll
        for (int d = 0; d < D; ++d) s += part[(d * B + b) * SC + j];
#pragma unroll
        for (int a = 0; a < ANT; ++a)
            s = fmaf(noise[(b * SC + j) * ANT + a], a_mat[j * ANT + a], s);
        z_s[w][j] = fmaxf(s, 0.f);
    }
    __syncthreads();

    // fc3: 98 outputs
    for (int o = lane; o < 98; o += 64) {
        float s = b3[o];
#pragma unroll
        for (int j = 0; j < SC; ++j) s = fmaf(z_s[w][j], w3[j * 98 + o], s);
        z3_s[w][o] = fmaxf(s, 0.f);
    }
    __syncthreads();

    // fc4: 49 outputs
    if (lane < 49) {
        float s = b4[lane];
        for (int j = 0; j < 98; ++j) s = fmaf(z3_s[w][j], w4[j * 49 + lane], s);
        z4_s[w][lane] = fmaxf(s, 0.f);
    }
    __syncthreads();

    // out: 10 logits + log_softmax across lanes 0..9 (16-lane shuffle group)
    float v = -INFINITY;
    if (lane < 10) {
        float s = bo[lane];
        for (int j = 0; j < 49; ++j) s = fmaf(z4_s[w][j], wo[j * 10 + lane], s);
        v = s;
    }
    float m = v;
#pragma unroll
    for (int off = 8; off >= 1; off >>= 1) m = fmaxf(m, __shfl_xor(m, off, 16));
    float e = (lane < 10) ? expf(v - m) : 0.f;
    float ssum = e;
#pragma unroll
    for (int off = 8; off >= 1; off >>= 1) ssum += __shfl_xor(ssum, off, 16);
    if (lane < 10) out[b * 10 + lane] = v - m - logf(ssum);
}

// ---------------------------------------------------------------------------
extern "C" void kernel_launch(void* const* d_in, const int* in_sizes, int n_in,
                              void* d_out, int out_size, void* d_ws, size_t ws_size,
                              hipStream_t stream) {
    const float* x      = (const float*)d_in[0];
    const float* noise  = (const float*)d_in[1];
    const float* sub_w  = (const float*)d_in[2];
    const float* sub_b  = (const float*)d_in[3];
    const float* ln_g   = (const float*)d_in[4];
    const float* ln_b   = (const float*)d_in[5];
    const float* cut_w  = (const float*)d_in[6];
    const float* cut_b  = (const float*)d_in[7];
    const float* b_mat  = (const float*)d_in[8];
    const float* h_mat  = (const float*)d_in[9];
    const float* a_mat  = (const float*)d_in[10];
    const float* clb    = (const float*)d_in[11];
    const float* fc3_w  = (const float*)d_in[12];
    const float* fc3_b  = (const float*)d_in[13];
    const float* fc4_w  = (const float*)d_in[14];
    const float* fc4_b  = (const float*)d_in[15];
    const float* out_w  = (const float*)d_in[16];
    const float* out_b  = (const float*)d_in[17];
    const int*   k_idx  = (const int*)d_in[18];
    float* out = (float*)d_out;

    float* part = (float*)d_ws;  // D*B*SC floats = 256000 (1 MB)

    k_main<<<D * NT, 512, 0, stream>>>(x, sub_w, sub_b, ln_g, ln_b, cut_w,
                                       cut_b, b_mat, h_mat, a_mat, k_idx, part);
    k_tail<<<B / 4, 256, 0, stream>>>(part, noise, a_mat, clb, fc3_w, fc3_b,
                                      fc4_w, fc4_b, out_w, out_b, out);
}

// Round 3
// 32.789 us; speedup vs baseline: 1.3898x; 1.3898x over previous
//
#include <hip/hip_runtime.h>
#include <math.h>

#define B 1000
#define D 8
#define PRE 98
#define NEXT 512
#define SC 32
#define ANT 5
#define BM 32
#define NT2 32            // ceil(1000/32)
#define KP 128            // PRE padded to 128 for MFMA K-steps

using bf16x8 = __attribute__((ext_vector_type(8))) short;
using f32x4  = __attribute__((ext_vector_type(4))) float;

static __device__ __forceinline__ unsigned short f2bf(float f) {
    union { float f; unsigned u; } v{f};
    unsigned r = (v.u + 0x7fffu + ((v.u >> 16) & 1u)) >> 16;
    return (unsigned short)r;
}
static __device__ __forceinline__ float bf2f(unsigned short h) {
    union { unsigned u; float f; } v{(unsigned)h << 16};
    return v.f;
}

// ---------------------------------------------------------------------------
// Prep: sub_wT[d][n][k] (bf16, k padded to 128 with 0) = sub_w[d][k][n]
//       cut_wT[d][c][k] (bf16)                         = cut_w[d][k][c]
// ---------------------------------------------------------------------------
__global__ __launch_bounds__(256) void k_prep(const float* __restrict__ sub_w,
                                              const float* __restrict__ cut_w,
                                              unsigned short* __restrict__ sub_wT,
                                              unsigned short* __restrict__ cut_wT) {
    __shared__ __align__(16) unsigned short tile[32][128];
    int t = threadIdx.x, bid = blockIdx.x;
    if (bid < 128) {                       // sub_w: (d, n-tile of 32), k = 0..127
        int d = bid >> 4, n0 = (bid & 15) * 32;
        int nn = t & 31, kk = t >> 5;      // kk 0..7
#pragma unroll
        for (int j = 0; j < 16; ++j) {
            int k = j * 8 + kk;
            float v = (k < PRE) ? sub_w[(d * PRE + k) * NEXT + n0 + nn] : 0.f;
            tile[nn][k] = f2bf(v);
        }
        __syncthreads();
        int row = t >> 3, c0 = (t & 7) * 16;
        unsigned short* dst = sub_wT + ((size_t)(d * NEXT + n0 + row)) * KP + c0;
        *reinterpret_cast<bf16x8*>(dst)     = *reinterpret_cast<bf16x8*>(&tile[row][c0]);
        *reinterpret_cast<bf16x8*>(dst + 8) = *reinterpret_cast<bf16x8*>(&tile[row][c0 + 8]);
    } else {                               // cut_w: (d, k-chunk of 128)
        int bb = bid - 128;                // 0..31
        int d = bb >> 2, k0 = (bb & 3) * 128;
        int nn = t & 31, kk = t >> 5;
#pragma unroll
        for (int j = 0; j < 16; ++j) {
            int kl = j * 8 + kk;
            tile[nn][kl] = f2bf(cut_w[(d * NEXT + k0 + kl) * SC + nn]);
        }
        __syncthreads();
        int row = t >> 3, c0 = (t & 7) * 16;
        unsigned short* dst = cut_wT + ((size_t)(d * SC + row)) * NEXT + k0 + c0;
        *reinterpret_cast<bf16x8*>(dst)     = *reinterpret_cast<bf16x8*>(&tile[row][c0]);
        *reinterpret_cast<bf16x8*>(dst + 8) = *reinterpret_cast<bf16x8*>(&tile[row][c0 + 8]);
    }
}

// ---------------------------------------------------------------------------
// k_main: per (d, 32-row tile): GEMM1 (MFMA) + bias/relu -> bf16 LDS ->
//         LayerNorm (register butterfly) -> GEMM2 (MFMA) -> part[d][b][c]
// 512 threads = 8 waves. Grid = D * 32 = 256 blocks.
// MFMA 16x16x32 bf16 layouts (m89/m91-verified):
//   A[m][k]: m = lane&15, k = (lane>>4)*8 + j   (8 contiguous bf16 = 16B)
//   B[k][n]: n = lane&15, k = (lane>>4)*8 + j
//   D[m][n]: n = lane&15, m = (lane>>4)*4 + reg
// ---------------------------------------------------------------------------
__global__ __launch_bounds__(512) void k_main(const float* __restrict__ x,
                                              const unsigned short* __restrict__ sub_wT,
                                              const float* __restrict__ sub_b,
                                              const float* __restrict__ gamma,
                                              const float* __restrict__ beta,
                                              const unsigned short* __restrict__ cut_wT,
                                              const float* __restrict__ cut_b,
                                              const float* __restrict__ b_mat,
                                              const float* __restrict__ h_mat,
                                              const float* __restrict__ a_mat,
                                              const int* __restrict__ k_idx,
                                              float* __restrict__ part) {
    __shared__ __align__(16) unsigned short x_lds[BM][136];  // K padded 128(+8 bank skew)
    __shared__ __align__(16) unsigned short h_lds[BM][536];  // 512(+24 bank skew)

    int t = threadIdx.x;
    int d = blockIdx.x >> 5;
    int tile = blockIdx.x & 31;
    int b0 = tile * BM;

    // ---- stage x tile -> bf16 LDS, zero-pad rows>=B and k in [98,136) ----
    for (int idx = t; idx < BM * 136; idx += 512) {
        int r = idx / 136, i = idx - r * 136;
        int b = b0 + r;
        float v = (b < B && i < PRE) ? x[b * (D * PRE) + d * PRE + i] : 0.f;
        x_lds[r][i] = f2bf(v);
    }
    __syncthreads();

    int w = t >> 6, lane = t & 63;
    int lr = lane >> 4, lc = lane & 15;

    // ---- GEMM1: (32x128) @ (128x512) ; wave -> 16x128 tile ----
    {
        int mt = w >> 2, nt = w & 3;
        int m0 = mt * 16, n0 = nt * 128;
        f32x4 acc[8] = {};
        const unsigned short* bw = sub_wT + (size_t)d * NEXT * KP + (size_t)(n0 + lc) * KP + lr * 8;
#pragma unroll
        for (int ks = 0; ks < 4; ++ks) {
            bf16x8 a = *reinterpret_cast<const bf16x8*>(&x_lds[m0 + lc][ks * 32 + lr * 8]);
            bf16x8 bq[8];
#pragma unroll
            for (int nf = 0; nf < 8; ++nf)
                bq[nf] = *reinterpret_cast<const bf16x8*>(bw + (size_t)nf * 16 * KP + ks * 32);
#pragma unroll
            for (int nf = 0; nf < 8; ++nf)
                acc[nf] = __builtin_amdgcn_mfma_f32_16x16x32_bf16(a, bq[nf], acc[nf], 0, 0, 0);
        }
        // bias + relu -> bf16 LDS
        const float* sb = sub_b + d * NEXT;
#pragma unroll
        for (int nf = 0; nf < 8; ++nf) {
            int n = n0 + nf * 16 + lc;
            float bias = sb[n];
#pragma unroll
            for (int r = 0; r < 4; ++r) {
                int m = m0 + lr * 4 + r;
                h_lds[m][n] = f2bf(fmaxf(acc[nf][r] + bias, 0.f));
            }
        }
    }
    __syncthreads();

    // ---- LayerNorm: 16 threads per row, butterfly reduce, normalize in place ----
    {
        int row = t >> 4, l16 = t & 15;
        unsigned int* hrow = reinterpret_cast<unsigned int*>(&h_lds[row][0]);
        float s1 = 0.f, s2 = 0.f;
#pragma unroll
        for (int j = 0; j < 16; ++j) {
            unsigned int p = hrow[l16 + j * 16];
            float v0 = bf2f((unsigned short)(p & 0xffffu));
            float v1 = bf2f((unsigned short)(p >> 16));
            s1 += v0 + v1;
            s2 += v0 * v0 + v1 * v1;
        }
#pragma unroll
        for (int off = 8; off >= 1; off >>= 1) {
            s1 += __shfl_xor(s1, off, 16);
            s2 += __shfl_xor(s2, off, 16);
        }
        float mu = s1 * (1.f / NEXT);
        float var = s2 * (1.f / NEXT) - mu * mu;
        float rs = rsqrtf(var + 1e-5f);
        const float* g = gamma + d * NEXT;
        const float* be = beta + d * NEXT;
#pragma unroll
        for (int j = 0; j < 16; ++j) {
            int pi = l16 + j * 16;
            unsigned int p = hrow[pi];
            int n = pi * 2;
            float v0 = (bf2f((unsigned short)(p & 0xffffu)) - mu) * rs * g[n] + be[n];
            float v1 = (bf2f((unsigned short)(p >> 16)) - mu) * rs * g[n + 1] + be[n + 1];
            hrow[pi] = (unsigned)f2bf(v0) | ((unsigned)f2bf(v1) << 16);
        }
    }
    __syncthreads();

    // ---- GEMM2: (32x512) @ (512x32) on waves 0..3 ; wave -> 16x16 tile ----
    if (w < 4) {
        int mt = w >> 1, nt = w & 1;
        f32x4 acc = {};
        const unsigned short* bw = cut_wT + (size_t)(d * SC + nt * 16 + lc) * NEXT + lr * 8;
#pragma unroll
        for (int ks = 0; ks < 16; ++ks) {
            bf16x8 a = *reinterpret_cast<const bf16x8*>(&h_lds[mt * 16 + lc][ks * 32 + lr * 8]);
            bf16x8 bq = *reinterpret_cast<const bf16x8*>(bw + ks * 32);
            acc = __builtin_amdgcn_mfma_f32_16x16x32_bf16(a, bq, acc, 0, 0, 0);
        }
        // coef for this lane's column c
        int c = nt * 16 + lc;
        int kk = k_idx[c];
        float hv = 0.f;
#pragma unroll
        for (int a = 0; a < ANT; ++a)
            hv = fmaf(h_mat[(d * SC + kk) * ANT + a], a_mat[c * ANT + a], hv);
        float cf = b_mat[d * SC + c] * hv;
        float cb = cut_b[d * SC + c];
#pragma unroll
        for (int r = 0; r < 4; ++r) {
            int m = mt * 16 + lr * 4 + r;
            int b = b0 + m;
            if (b < B) part[(d * B + b) * SC + c] = fmaxf(acc[r] + cb, 0.f) * cf;
        }
    }
}

// ---------------------------------------------------------------------------
// k_tail: one wave per row b. B = 1000 = 250 blocks * 4 waves.
// ---------------------------------------------------------------------------
__global__ __launch_bounds__(256) void k_tail(const float* __restrict__ part,
                                              const float* __restrict__ noise,
                                              const float* __restrict__ a_mat,
                                              const float* __restrict__ clb,
                                              const float* __restrict__ fc3_w,
                                              const float* __restrict__ fc3_b,
                                              const float* __restrict__ fc4_w,
                                              const float* __restrict__ fc4_b,
                                              const float* __restrict__ out_w,
                                              const float* __restrict__ out_b,
                                              float* __restrict__ out) {
    __shared__ float w3[SC * 98];
    __shared__ float w4[98 * 49];
    __shared__ float wo[49 * 10];
    __shared__ float b3[98], b4[49], bo[10];
    __shared__ float z_s[4][SC];
    __shared__ float z3_s[4][98];
    __shared__ float z4_s[4][49];

    int t = threadIdx.x;
    for (int i = t; i < SC * 98; i += 256) w3[i] = fc3_w[i];
    for (int i = t; i < 98 * 49; i += 256) w4[i] = fc4_w[i];
    for (int i = t; i < 49 * 10; i += 256) wo[i] = out_w[i];
    if (t < 98) b3[t] = fc3_b[t];
    if (t < 49) b4[t] = fc4_b[t];
    if (t < 10) bo[t] = out_b[t];
    __syncthreads();

    int w = t >> 6, lane = t & 63;
    int b = blockIdx.x * 4 + w;

    if (lane < SC) {
        int j = lane;
        float s = clb[j];
#pragma unroll
        for (int d = 0; d < D; ++d) s += part[(d * B + b) * SC + j];
#pragma unroll
        for (int a = 0; a < ANT; ++a)
            s = fmaf(noise[(b * SC + j) * ANT + a], a_mat[j * ANT + a], s);
        z_s[w][j] = fmaxf(s, 0.f);
    }
    __syncthreads();

    for (int o = lane; o < 98; o += 64) {
        float s = b3[o];
#pragma unroll
        for (int j = 0; j < SC; ++j) s = fmaf(z_s[w][j], w3[j * 98 + o], s);
        z3_s[w][o] = fmaxf(s, 0.f);
    }
    __syncthreads();

    if (lane < 49) {
        float s = b4[lane];
        for (int j = 0; j < 98; ++j) s = fmaf(z3_s[w][j], w4[j * 49 + lane], s);
        z4_s[w][lane] = fmaxf(s, 0.f);
    }
    __syncthreads();

    float v = -INFINITY;
    if (lane < 10) {
        float s = bo[lane];
        for (int j = 0; j < 49; ++j) s = fmaf(z4_s[w][j], wo[j * 10 + lane], s);
        v = s;
    }
    float m = v;
#pragma unroll
    for (int off = 8; off >= 1; off >>= 1) m = fmaxf(m, __shfl_xor(m, off, 16));
    float e = (lane < 10) ? expf(v - m) : 0.f;
    float ssum = e;
#pragma unroll
    for (int off = 8; off >= 1; off >>= 1) ssum += __shfl_xor(ssum, off, 16);
    if (lane < 10) out[b * 10 + lane] = v - m - logf(ssum);
}

// ---------------------------------------------------------------------------
extern "C" void kernel_launch(void* const* d_in, const int* in_sizes, int n_in,
                              void* d_out, int out_size, void* d_ws, size_t ws_size,
                              hipStream_t stream) {
    const float* x      = (const float*)d_in[0];
    const float* noise  = (const float*)d_in[1];
    const float* sub_w  = (const float*)d_in[2];
    const float* sub_b  = (const float*)d_in[3];
    const float* ln_g   = (const float*)d_in[4];
    const float* ln_b   = (const float*)d_in[5];
    const float* cut_w  = (const float*)d_in[6];
    const float* cut_b  = (const float*)d_in[7];
    const float* b_mat  = (const float*)d_in[8];
    const float* h_mat  = (const float*)d_in[9];
    const float* a_mat  = (const float*)d_in[10];
    const float* clb    = (const float*)d_in[11];
    const float* fc3_w  = (const float*)d_in[12];
    const float* fc3_b  = (const float*)d_in[13];
    const float* fc4_w  = (const float*)d_in[14];
    const float* fc4_b  = (const float*)d_in[15];
    const float* out_w  = (const float*)d_in[16];
    const float* out_b  = (const float*)d_in[17];
    const int*   k_idx  = (const int*)d_in[18];
    float* out = (float*)d_out;

    char* ws = (char*)d_ws;
    float* part            = (float*)ws;                   // 1,024,000 B
    unsigned short* sub_wT = (unsigned short*)(ws + (1 << 20));   // 1,048,576 B
    unsigned short* cut_wT = (unsigned short*)(ws + (2 << 20));   // 262,144 B

    k_prep<<<160, 256, 0, stream>>>(sub_w, cut_w, sub_wT, cut_wT);
    k_main<<<D * NT2, 512, 0, stream>>>(x, sub_wT, sub_b, ln_g, ln_b, cut_wT,
                                        cut_b, b_mat, h_mat, a_mat, k_idx, part);
    k_tail<<<B / 4, 256, 0, stream>>>(part, noise, a_mat, clb, fc3_w, fc3_b,
                                      fc4_w, fc4_b, out_w, out_b, out);
}